// Round 5
// baseline (269.419 us; speedup 1.0000x reference)
//
#include <hip/hip_runtime.h>
#include <hip/hip_bf16.h>
#include <math.h>

typedef __bf16 bf16;
typedef __attribute__((ext_vector_type(8))) __bf16 bf16x8;
typedef __attribute__((ext_vector_type(4))) __bf16 bf16x4;
typedef __attribute__((ext_vector_type(4))) float f32x4;

#define MFMA16(a, b, c) __builtin_amdgcn_mfma_f32_16x16x32_bf16((a), (b), (c), 0, 0, 0)

// ---------------------------------------------------------------------------
// f32 -> bf16 cast, 4 elems/thread
// ---------------------------------------------------------------------------
__global__ __launch_bounds__(256) void cvt_f32_bf16(const float* __restrict__ in,
                                                    bf16* __restrict__ out, int n4) {
  int i = blockIdx.x * 256 + threadIdx.x;
  if (i < n4) {
    float4 v = ((const float4*)in)[i];
    bf16x4 o = {(bf16)v.x, (bf16)v.y, (bf16)v.z, (bf16)v.w};
    ((bf16x4*)out)[i] = o;
  }
}

// ---------------------------------------------------------------------------
// GEMM, C[m,n] = sum_k A[m,k]*B[n,k]  (both row-major, "B^T" layout)
// BM=BN=128, BK=64, 256 threads = 4 waves in 2x2, each wave 64x64 out.
// If Cb != nullptr: write bf16 to Cb. Else: write f32 + bias to Cf.
// ---------------------------------------------------------------------------
__global__ __launch_bounds__(256) void gemm_bt(const bf16* __restrict__ A,
                                               const bf16* __restrict__ Bm,
                                               float* __restrict__ Cf,
                                               bf16* __restrict__ Cb,
                                               const float* __restrict__ bias,
                                               int M, int N, int K) {
  __shared__ __align__(16) bf16 As[128 * 64];
  __shared__ __align__(16) bf16 Bs[128 * 64];
  const int t = threadIdx.x;
  const int w = t >> 6, l = t & 63;
  const int wr = w >> 1, wc = w & 1;
  const int lr = l & 15, lh = l >> 4;
  const int bm = blockIdx.x * 128, bn = blockIdx.y * 128;
  const int r0 = t >> 2, c0 = (t & 3) * 16;

  f32x4 acc[4][4] = {};

  for (int k0 = 0; k0 < K; k0 += 64) {
    __syncthreads();
    // stage full 128x64 tiles: 2 rows x 16 cols per thread
#pragma unroll
    for (int rr = 0; rr < 2; ++rr) {
      const int r = r0 + rr * 64;
      *(bf16x8*)(As + r * 64 + c0)     = *(const bf16x8*)(A + (size_t)(bm + r) * K + k0 + c0);
      *(bf16x8*)(As + r * 64 + c0 + 8) = *(const bf16x8*)(A + (size_t)(bm + r) * K + k0 + c0 + 8);
      *(bf16x8*)(Bs + r * 64 + c0)     = *(const bf16x8*)(Bm + (size_t)(bn + r) * K + k0 + c0);
      *(bf16x8*)(Bs + r * 64 + c0 + 8) = *(const bf16x8*)(Bm + (size_t)(bn + r) * K + k0 + c0 + 8);
    }
    __syncthreads();
#pragma unroll
    for (int kk = 0; kk < 2; ++kk) {
      bf16x8 af[4], bfr[4];
#pragma unroll
      for (int mt = 0; mt < 4; ++mt)
        af[mt] = *(const bf16x8*)(As + (wr * 64 + mt * 16 + lr) * 64 + kk * 32 + lh * 8);
#pragma unroll
      for (int nt = 0; nt < 4; ++nt)
        bfr[nt] = *(const bf16x8*)(Bs + (wc * 64 + nt * 16 + lr) * 64 + kk * 32 + lh * 8);
#pragma unroll
      for (int mt = 0; mt < 4; ++mt)
#pragma unroll
        for (int nt = 0; nt < 4; ++nt)
          acc[mt][nt] = MFMA16(af[mt], bfr[nt], acc[mt][nt]);
    }
  }

#pragma unroll
  for (int mt = 0; mt < 4; ++mt)
#pragma unroll
    for (int nt = 0; nt < 4; ++nt)
#pragma unroll
      for (int r = 0; r < 4; ++r) {
        int m = bm + wr * 64 + mt * 16 + lh * 4 + r;
        int n = bn + wc * 64 + nt * 16 + lr;
        if (Cb) Cb[(size_t)m * N + n] = (bf16)acc[mt][nt][r];
        else    Cf[(size_t)m * N + n] = acc[mt][nt][r] + bias[n];
      }
}

// ---------------------------------------------------------------------------
// RoPE + repack qkv[b,s, t*1024 + h*64 + d] -> Q/K/V [b*16+h][s][d] (bf16)
// one thread per (bh, s, j) with j in [0,32): handles pair (j, j+32)
// ---------------------------------------------------------------------------
__global__ __launch_bounds__(256) void rope_repack(const bf16* __restrict__ qkv,
                                                   bf16* __restrict__ Qd,
                                                   bf16* __restrict__ Kd,
                                                   bf16* __restrict__ Vd) {
  int idx = blockIdx.x * 256 + threadIdx.x;
  int j = idx & 31;
  int s = (idx >> 5) & 2047;
  int bh = idx >> 16;           // 0..31
  int b = bh >> 4, h = bh & 15;
  const bf16* row = qkv + (size_t)(b * 2048 + s) * 3072;
  int base = h * 64 + j;
  float q1 = (float)row[base],        q2 = (float)row[base + 32];
  float k1 = (float)row[1024 + base], k2 = (float)row[1024 + base + 32];
  float v1 = (float)row[2048 + base], v2 = (float)row[2048 + base + 32];
  // inv_freq = 10000^(-j/32) = exp(-j * ln(10000)/32)
  float inv_freq = expf((float)j * -0.28782313662425575f);
  float ang = (float)s * inv_freq;
  float c = cosf(ang), sn = sinf(ang);
  size_t o = ((size_t)bh * 2048 + s) * 64 + j;
  Qd[o]      = (bf16)(q1 * c - q2 * sn);
  Qd[o + 32] = (bf16)(q2 * c + q1 * sn);
  Kd[o]      = (bf16)(k1 * c - k2 * sn);
  Kd[o + 32] = (bf16)(k2 * c + k1 * sn);
  Vd[o]      = (bf16)v1;
  Vd[o + 32] = (bf16)v2;
}

// ---------------------------------------------------------------------------
// Flash attention fwd. grid = (B*H=32, S/64=32). 256 thr = 4 waves.
// Wave w owns q rows [qt*64 + 16w, +16). KV tiles of 64.
// ---------------------------------------------------------------------------
__global__ __launch_bounds__(256) void attn_fwd(const bf16* __restrict__ Qg,
                                                const bf16* __restrict__ Kg,
                                                const bf16* __restrict__ Vg,
                                                bf16* __restrict__ Og) {
  __shared__ __align__(16) bf16 Ks[64 * 64];
  __shared__ __align__(16) bf16 Vt[64 * 64];   // transposed: Vt[d][j]
  __shared__ __align__(16) bf16 Ps[64 * 64];
  const int bh = blockIdx.x, qt = blockIdx.y;
  const int t = threadIdx.x, w = t >> 6, l = t & 63;
  const int lr = l & 15, lh = l >> 4;
  const bf16* Qb = Qg + (size_t)bh * 2048 * 64;
  const bf16* Kb = Kg + (size_t)bh * 2048 * 64;
  const bf16* Vb = Vg + (size_t)bh * 2048 * 64;

  // Q fragments (A-operand layout: row = lr, k = lh*8 + e), held in regs
  bf16x8 qf[2];
  {
    int qrow = qt * 64 + w * 16 + lr;
    qf[0] = *(const bf16x8*)(Qb + (size_t)qrow * 64 + lh * 8);
    qf[1] = *(const bf16x8*)(Qb + (size_t)qrow * 64 + lh * 8 + 32);
  }

  float mrow[4], lrow[4];
#pragma unroll
  for (int r = 0; r < 4; ++r) { mrow[r] = -INFINITY; lrow[r] = 0.f; }
  f32x4 acc[4] = {};

  const int r0 = t >> 2, c0 = (t & 3) * 16;
  for (int kv = 0; kv < 2048; kv += 64) {
    __syncthreads();
    // stage K rows (linear) and V transposed
    *(bf16x8*)(Ks + r0 * 64 + c0)     = *(const bf16x8*)(Kb + (size_t)(kv + r0) * 64 + c0);
    *(bf16x8*)(Ks + r0 * 64 + c0 + 8) = *(const bf16x8*)(Kb + (size_t)(kv + r0) * 64 + c0 + 8);
    bf16x8 v0 = *(const bf16x8*)(Vb + (size_t)(kv + r0) * 64 + c0);
    bf16x8 v1 = *(const bf16x8*)(Vb + (size_t)(kv + r0) * 64 + c0 + 8);
#pragma unroll
    for (int e = 0; e < 8; ++e) {
      Vt[(c0 + e) * 64 + r0]     = v0[e];
      Vt[(c0 + 8 + e) * 64 + r0] = v1[e];
    }
    __syncthreads();

    // scores S = Q K^T (16x64 per wave)
    f32x4 sc[4] = {};
#pragma unroll
    for (int kk = 0; kk < 2; ++kk) {
#pragma unroll
      for (int nt = 0; nt < 4; ++nt) {
        bf16x8 bfr = *(const bf16x8*)(Ks + (nt * 16 + lr) * 64 + kk * 32 + lh * 8);
        sc[nt] = MFMA16(qf[kk], bfr, sc[nt]);
      }
    }

    // online softmax, rows i = lh*4 + r, cols nt*16 + lr
#pragma unroll
    for (int r = 0; r < 4; ++r) {
      float s0 = sc[0][r] * 0.125f, s1 = sc[1][r] * 0.125f;
      float s2 = sc[2][r] * 0.125f, s3 = sc[3][r] * 0.125f;
      float mx = fmaxf(fmaxf(s0, s1), fmaxf(s2, s3));
#pragma unroll
      for (int off = 1; off < 16; off <<= 1)
        mx = fmaxf(mx, __shfl_xor(mx, off, 16));
      float mnew = fmaxf(mrow[r], mx);
      float alpha = __expf(mrow[r] - mnew);
      mrow[r] = mnew;
      float p0 = __expf(s0 - mnew), p1 = __expf(s1 - mnew);
      float p2 = __expf(s2 - mnew), p3 = __expf(s3 - mnew);
      float psum = p0 + p1 + p2 + p3;
#pragma unroll
      for (int off = 1; off < 16; off <<= 1)
        psum += __shfl_xor(psum, off, 16);
      lrow[r] = lrow[r] * alpha + psum;
#pragma unroll
      for (int nt = 0; nt < 4; ++nt) acc[nt][r] *= alpha;
      int prow = w * 16 + lh * 4 + r;
      Ps[prow * 64 + lr]      = (bf16)p0;
      Ps[prow * 64 + 16 + lr] = (bf16)p1;
      Ps[prow * 64 + 32 + lr] = (bf16)p2;
      Ps[prow * 64 + 48 + lr] = (bf16)p3;
    }
    // make this wave's Ps writes visible to its own lanes' ds_reads
    asm volatile("s_waitcnt lgkmcnt(0)" ::: "memory");

    // O += P V  (A = P from Ps, B = V via Vt)
#pragma unroll
    for (int kk = 0; kk < 2; ++kk) {
      bf16x8 pa = *(const bf16x8*)(Ps + (w * 16 + lr) * 64 + kk * 32 + lh * 8);
#pragma unroll
      for (int nt = 0; nt < 4; ++nt) {
        bf16x8 bv = *(const bf16x8*)(Vt + (nt * 16 + lr) * 64 + kk * 32 + lh * 8);
        acc[nt] = MFMA16(pa, bv, acc[nt]);
      }
    }
  }

  // epilogue: Og[b, s, h*64+d] = acc / l
  const int b = bh >> 4, h = bh & 15;
#pragma unroll
  for (int nt = 0; nt < 4; ++nt)
#pragma unroll
    for (int r = 0; r < 4; ++r) {
      int row = qt * 64 + w * 16 + lh * 4 + r;
      int col = h * 64 + nt * 16 + lr;
      Og[((size_t)(b * 2048 + row)) * 1024 + col] = (bf16)(acc[nt][r] / lrow[r]);
    }
}

// ---------------------------------------------------------------------------
extern "C" void kernel_launch(void* const* d_in, const int* in_sizes, int n_in,
                              void* d_out, int out_size, void* d_ws, size_t ws_size,
                              hipStream_t stream) {
  const float* x     = (const float*)d_in[0];  // [2,2048,1024]
  const float* w_qkv = (const float*)d_in[1];  // [3072,1024]
  const float* w_out = (const float*)d_in[2];  // [1024,1024]
  const float* b_out = (const float*)d_in[3];  // [1024]
  float* out = (float*)d_out;
  char* ws = (char*)d_ws;
  const size_t MB = 1024 * 1024;

  bf16* xb    = (bf16*)(ws);            // 8 MB (x bf16)
  bf16* wqkvb = (bf16*)(ws + 8 * MB);   // 6 MB
  bf16* woutb = (bf16*)(ws + 14 * MB);  // 2 MB
  bf16* qkvb  = (bf16*)(ws + 16 * MB);  // 24 MB
  bf16* Qd    = (bf16*)(ws + 40 * MB);  // 8 MB
  bf16* Kd    = (bf16*)(ws + 48 * MB);  // 8 MB
  bf16* Vd    = (bf16*)(ws + 56 * MB);  // 8 MB
  bf16* attnb = xb;                     // reuse x slot after gemm_qkv consumed it

  cvt_f32_bf16<<<4096, 256, 0, stream>>>(x, xb, 1048576);
  cvt_f32_bf16<<<3072, 256, 0, stream>>>(w_qkv, wqkvb, 786432);
  cvt_f32_bf16<<<1024, 256, 0, stream>>>(w_out, woutb, 262144);

  // qkv = x @ w_qkv^T : M=4096, N=3072, K=1024  -> bf16
  gemm_bt<<<dim3(32, 24), 256, 0, stream>>>(xb, wqkvb, nullptr, qkvb, nullptr,
                                            4096, 3072, 1024);
  rope_repack<<<8192, 256, 0, stream>>>(qkvb, Qd, Kd, Vd);
  attn_fwd<<<dim3(32, 32), 256, 0, stream>>>(Qd, Kd, Vd, attnb);
  // out = attn @ w_out^T + b : M=4096, N=1024, K=1024 -> f32
  gemm_bt<<<dim3(32, 8), 256, 0, stream>>>(attnb, woutb, out, nullptr, b_out,
                                           4096, 1024, 1024);
}

// Round 6
// 195.709 us; speedup vs baseline: 1.3766x; 1.3766x over previous
//
#include <hip/hip_runtime.h>
#include <hip/hip_bf16.h>
#include <math.h>

typedef __bf16 bf16;
typedef __attribute__((ext_vector_type(8))) __bf16 bf16x8;
typedef __attribute__((ext_vector_type(4))) __bf16 bf16x4;
typedef __attribute__((ext_vector_type(4))) float f32x4;

#define MFMA16(a, b, c) __builtin_amdgcn_mfma_f32_16x16x32_bf16((a), (b), (c), 0, 0, 0)

// XOR swizzle for [rows][64] bf16 LDS tiles (128 B row = 32 banks exactly).
// 16B chunk index (col>>3) XOR'd with (row&7): spreads 8 consecutive rows
// across 8 distinct 16B slots -> bank conflicts 16-way -> free (2-way).
__device__ __forceinline__ int swz(int row, int col) {
  return row * 64 + ((((col) >> 3) ^ (row & 7)) << 3) + (col & 7);
}

// ---------------------------------------------------------------------------
// f32 -> bf16 cast, 4 elems/thread
// ---------------------------------------------------------------------------
__global__ __launch_bounds__(256) void cvt_f32_bf16(const float* __restrict__ in,
                                                    bf16* __restrict__ out, int n4) {
  int i = blockIdx.x * 256 + threadIdx.x;
  if (i < n4) {
    float4 v = ((const float4*)in)[i];
    bf16x4 o = {(bf16)v.x, (bf16)v.y, (bf16)v.z, (bf16)v.w};
    ((bf16x4*)out)[i] = o;
  }
}

// ---------------------------------------------------------------------------
// GEMM, C[m,n] = sum_k A[m,k]*B[n,k]  (both row-major, "B^T" layout)
// BM=BN=128, BK=64, 256 threads = 4 waves in 2x2, each wave 64x64 out.
// LDS tiles XOR-swizzled on both write and read side.
// ---------------------------------------------------------------------------
__global__ __launch_bounds__(256) void gemm_bt(const bf16* __restrict__ A,
                                               const bf16* __restrict__ Bm,
                                               float* __restrict__ Cf,
                                               bf16* __restrict__ Cb,
                                               const float* __restrict__ bias,
                                               int M, int N, int K) {
  __shared__ __align__(16) bf16 As[128 * 64];
  __shared__ __align__(16) bf16 Bs[128 * 64];
  const int t = threadIdx.x;
  const int w = t >> 6, l = t & 63;
  const int wr = w >> 1, wc = w & 1;
  const int lr = l & 15, lh = l >> 4;
  const int bm = blockIdx.x * 128, bn = blockIdx.y * 128;
  const int r0 = t >> 2, c0 = (t & 3) * 16;

  f32x4 acc[4][4] = {};

  for (int k0 = 0; k0 < K; k0 += 64) {
    __syncthreads();
    // stage full 128x64 tiles: 2 rows x 16 cols per thread, swizzled writes
#pragma unroll
    for (int rr = 0; rr < 2; ++rr) {
      const int r = r0 + rr * 64;
      *(bf16x8*)(As + swz(r, c0))     = *(const bf16x8*)(A + (size_t)(bm + r) * K + k0 + c0);
      *(bf16x8*)(As + swz(r, c0 + 8)) = *(const bf16x8*)(A + (size_t)(bm + r) * K + k0 + c0 + 8);
      *(bf16x8*)(Bs + swz(r, c0))     = *(const bf16x8*)(Bm + (size_t)(bn + r) * K + k0 + c0);
      *(bf16x8*)(Bs + swz(r, c0 + 8)) = *(const bf16x8*)(Bm + (size_t)(bn + r) * K + k0 + c0 + 8);
    }
    __syncthreads();
#pragma unroll
    for (int kk = 0; kk < 2; ++kk) {
      bf16x8 af[4], bfr[4];
#pragma unroll
      for (int mt = 0; mt < 4; ++mt)
        af[mt] = *(const bf16x8*)(As + swz(wr * 64 + mt * 16 + lr, kk * 32 + lh * 8));
#pragma unroll
      for (int nt = 0; nt < 4; ++nt)
        bfr[nt] = *(const bf16x8*)(Bs + swz(wc * 64 + nt * 16 + lr, kk * 32 + lh * 8));
#pragma unroll
      for (int mt = 0; mt < 4; ++mt)
#pragma unroll
        for (int nt = 0; nt < 4; ++nt)
          acc[mt][nt] = MFMA16(af[mt], bfr[nt], acc[mt][nt]);
    }
  }

#pragma unroll
  for (int mt = 0; mt < 4; ++mt)
#pragma unroll
    for (int nt = 0; nt < 4; ++nt)
#pragma unroll
      for (int r = 0; r < 4; ++r) {
        int m = bm + wr * 64 + mt * 16 + lh * 4 + r;
        int n = bn + wc * 64 + nt * 16 + lr;
        if (Cb) Cb[(size_t)m * N + n] = (bf16)acc[mt][nt][r];
        else    Cf[(size_t)m * N + n] = acc[mt][nt][r] + bias[n];
      }
}

// ---------------------------------------------------------------------------
// RoPE + repack qkv[b,s, t*1024 + h*64 + d] -> Q/K [b*16+h][s][d] (bf16)
// (V handled by v_transpose). thread: (bh, s, j), j in [0,32) pair (j, j+32)
// ---------------------------------------------------------------------------
__global__ __launch_bounds__(256) void rope_repack(const bf16* __restrict__ qkv,
                                                   bf16* __restrict__ Qd,
                                                   bf16* __restrict__ Kd) {
  int idx = blockIdx.x * 256 + threadIdx.x;
  int j = idx & 31;
  int s = (idx >> 5) & 2047;
  int bh = idx >> 16;           // 0..31
  int b = bh >> 4, h = bh & 15;
  const bf16* row = qkv + (size_t)(b * 2048 + s) * 3072;
  int base = h * 64 + j;
  float q1 = (float)row[base],        q2 = (float)row[base + 32];
  float k1 = (float)row[1024 + base], k2 = (float)row[1024 + base + 32];
  float inv_freq = expf((float)j * -0.28782313662425575f);
  float ang = (float)s * inv_freq;
  float c = cosf(ang), sn = sinf(ang);
  size_t o = ((size_t)bh * 2048 + s) * 64 + j;
  Qd[o]      = (bf16)(q1 * c - q2 * sn);
  Qd[o + 32] = (bf16)(q2 * c + q1 * sn);
  Kd[o]      = (bf16)(k1 * c - k2 * sn);
  Kd[o + 32] = (bf16)(k2 * c + k1 * sn);
}

// ---------------------------------------------------------------------------
// V transpose (done ONCE, not per qt-block): qkv V-part -> Vt_g[bh][d][s].
// lane d = t&63: per-instr lanes read 128 B contiguous of a qkv row.
// grid = 32 bh * 64 s-chunks of 32.
// ---------------------------------------------------------------------------
__global__ __launch_bounds__(256) void v_transpose(const bf16* __restrict__ qkv,
                                                   bf16* __restrict__ Vtg) {
  const int bx = blockIdx.x;
  const int bh = bx >> 6, sc = bx & 63;
  const int b = bh >> 4, h = bh & 15;
  const int t = threadIdx.x;
  const int d = t & 63, w = t >> 6;
  const int s0 = sc * 32 + w * 8;
  bf16 vals[8];
#pragma unroll
  for (int e = 0; e < 8; ++e)
    vals[e] = qkv[(size_t)(b * 2048 + s0 + e) * 3072 + 2048 + h * 64 + d];
  *(bf16x8*)(Vtg + (size_t)bh * 131072 + (size_t)d * 2048 + s0) = *(bf16x8*)vals;
}

// ---------------------------------------------------------------------------
// Flash attention fwd. grid = (B*H=32, S/64=32). 256 thr = 4 waves.
// Wave w owns q rows [qt*64 + 16w, +16). KV tiles of 64. All LDS swizzled.
// V comes pre-transposed from global (Vtg[bh][d][s]).
// ---------------------------------------------------------------------------
__global__ __launch_bounds__(256) void attn_fwd(const bf16* __restrict__ Qg,
                                                const bf16* __restrict__ Kg,
                                                const bf16* __restrict__ Vtg,
                                                bf16* __restrict__ Og) {
  __shared__ __align__(16) bf16 Ks[64 * 64];
  __shared__ __align__(16) bf16 Vt[64 * 64];   // Vt[d][j] (kv-local), swizzled
  __shared__ __align__(16) bf16 Ps[64 * 64];
  const int bh = blockIdx.x, qt = blockIdx.y;
  const int t = threadIdx.x, w = t >> 6, l = t & 63;
  const int lr = l & 15, lh = l >> 4;
  const bf16* Qb  = Qg  + (size_t)bh * 2048 * 64;
  const bf16* Kb  = Kg  + (size_t)bh * 2048 * 64;
  const bf16* Vtb = Vtg + (size_t)bh * 131072;   // [64 d][2048 s]

  // Q fragments (A-operand layout: row = lr, k = lh*8 + e), held in regs
  bf16x8 qf[2];
  {
    int qrow = qt * 64 + w * 16 + lr;
    qf[0] = *(const bf16x8*)(Qb + (size_t)qrow * 64 + lh * 8);
    qf[1] = *(const bf16x8*)(Qb + (size_t)qrow * 64 + lh * 8 + 32);
  }

  float mrow[4], lrow[4];
#pragma unroll
  for (int r = 0; r < 4; ++r) { mrow[r] = -INFINITY; lrow[r] = 0.f; }
  f32x4 acc[4] = {};

  const int r0 = t >> 2, c0 = (t & 3) * 16;
  for (int kv = 0; kv < 2048; kv += 64) {
    __syncthreads();
    // stage K rows and V^T rows — both vectorized, swizzled writes
    *(bf16x8*)(Ks + swz(r0, c0))     = *(const bf16x8*)(Kb + (size_t)(kv + r0) * 64 + c0);
    *(bf16x8*)(Ks + swz(r0, c0 + 8)) = *(const bf16x8*)(Kb + (size_t)(kv + r0) * 64 + c0 + 8);
    *(bf16x8*)(Vt + swz(r0, c0))     = *(const bf16x8*)(Vtb + (size_t)r0 * 2048 + kv + c0);
    *(bf16x8*)(Vt + swz(r0, c0 + 8)) = *(const bf16x8*)(Vtb + (size_t)r0 * 2048 + kv + c0 + 8);
    __syncthreads();

    // scores S = Q K^T (16x64 per wave)
    f32x4 sc[4] = {};
#pragma unroll
    for (int kk = 0; kk < 2; ++kk) {
#pragma unroll
      for (int nt = 0; nt < 4; ++nt) {
        bf16x8 bfr = *(const bf16x8*)(Ks + swz(nt * 16 + lr, kk * 32 + lh * 8));
        sc[nt] = MFMA16(qf[kk], bfr, sc[nt]);
      }
    }

    // online softmax, rows i = lh*4 + r, cols nt*16 + lr
#pragma unroll
    for (int r = 0; r < 4; ++r) {
      float s0 = sc[0][r] * 0.125f, s1 = sc[1][r] * 0.125f;
      float s2 = sc[2][r] * 0.125f, s3 = sc[3][r] * 0.125f;
      float mx = fmaxf(fmaxf(s0, s1), fmaxf(s2, s3));
#pragma unroll
      for (int off = 1; off < 16; off <<= 1)
        mx = fmaxf(mx, __shfl_xor(mx, off, 16));
      float mnew = fmaxf(mrow[r], mx);
      float alpha = __expf(mrow[r] - mnew);
      mrow[r] = mnew;
      float p0 = __expf(s0 - mnew), p1 = __expf(s1 - mnew);
      float p2 = __expf(s2 - mnew), p3 = __expf(s3 - mnew);
      float psum = p0 + p1 + p2 + p3;
#pragma unroll
      for (int off = 1; off < 16; off <<= 1)
        psum += __shfl_xor(psum, off, 16);
      lrow[r] = lrow[r] * alpha + psum;
#pragma unroll
      for (int nt = 0; nt < 4; ++nt) acc[nt][r] *= alpha;
      int prow = w * 16 + lh * 4 + r;
      Ps[swz(prow, lr)]      = (bf16)p0;
      Ps[swz(prow, 16 + lr)] = (bf16)p1;
      Ps[swz(prow, 32 + lr)] = (bf16)p2;
      Ps[swz(prow, 48 + lr)] = (bf16)p3;
    }
    // make this wave's Ps writes visible to its own lanes' ds_reads
    asm volatile("s_waitcnt lgkmcnt(0)" ::: "memory");

    // O += P V  (A = P from Ps, B = V via Vt)
#pragma unroll
    for (int kk = 0; kk < 2; ++kk) {
      bf16x8 pa = *(const bf16x8*)(Ps + swz(w * 16 + lr, kk * 32 + lh * 8));
#pragma unroll
      for (int nt = 0; nt < 4; ++nt) {
        bf16x8 bv = *(const bf16x8*)(Vt + swz(nt * 16 + lr, kk * 32 + lh * 8));
        acc[nt] = MFMA16(pa, bv, acc[nt]);
      }
    }
  }

  // epilogue: Og[b, s, h*64+d] = acc / l
  const int b = bh >> 4, h = bh & 15;
#pragma unroll
  for (int nt = 0; nt < 4; ++nt)
#pragma unroll
    for (int r = 0; r < 4; ++r) {
      int row = qt * 64 + w * 16 + lh * 4 + r;
      int col = h * 64 + nt * 16 + lr;
      Og[((size_t)(b * 2048 + row)) * 1024 + col] = (bf16)(acc[nt][r] / lrow[r]);
    }
}

// ---------------------------------------------------------------------------
extern "C" void kernel_launch(void* const* d_in, const int* in_sizes, int n_in,
                              void* d_out, int out_size, void* d_ws, size_t ws_size,
                              hipStream_t stream) {
  const float* x     = (const float*)d_in[0];  // [2,2048,1024]
  const float* w_qkv = (const float*)d_in[1];  // [3072,1024]
  const float* w_out = (const float*)d_in[2];  // [1024,1024]
  const float* b_out = (const float*)d_in[3];  // [1024]
  float* out = (float*)d_out;
  char* ws = (char*)d_ws;
  const size_t MB = 1024 * 1024;

  bf16* xb    = (bf16*)(ws);            // 8 MB (x bf16)
  bf16* wqkvb = (bf16*)(ws + 8 * MB);   // 6 MB
  bf16* woutb = (bf16*)(ws + 14 * MB);  // 2 MB
  bf16* qkvb  = (bf16*)(ws + 16 * MB);  // 24 MB
  bf16* Qd    = (bf16*)(ws + 40 * MB);  // 8 MB
  bf16* Kd    = (bf16*)(ws + 48 * MB);  // 8 MB
  bf16* Vtg   = (bf16*)(ws + 56 * MB);  // 8 MB  V^T [bh][d][s]
  bf16* attnb = xb;                     // reuse x slot after gemm_qkv consumed it

  cvt_f32_bf16<<<4096, 256, 0, stream>>>(x, xb, 1048576);
  cvt_f32_bf16<<<3072, 256, 0, stream>>>(w_qkv, wqkvb, 786432);
  cvt_f32_bf16<<<1024, 256, 0, stream>>>(w_out, woutb, 262144);

  // qkv = x @ w_qkv^T : M=4096, N=3072, K=1024  -> bf16
  gemm_bt<<<dim3(32, 24), 256, 0, stream>>>(xb, wqkvb, nullptr, qkvb, nullptr,
                                            4096, 3072, 1024);
  rope_repack<<<8192, 256, 0, stream>>>(qkvb, Qd, Kd);
  v_transpose<<<2048, 256, 0, stream>>>(qkvb, Vtg);
  attn_fwd<<<dim3(32, 32), 256, 0, stream>>>(Qd, Kd, Vtg, attnb);
  // out = attn @ w_out^T + b : M=4096, N=1024, K=1024 -> f32
  gemm_bt<<<dim3(32, 8), 256, 0, stream>>>(attnb, woutb, out, nullptr, b_out,
                                           4096, 1024, 1024);
}